// Round 9
// baseline (384.393 us; speedup 1.0000x reference)
//
#include <hip/hip_runtime.h>
#include <stdint.h>
#include <stddef.h>

// Problem constants (MultiHeadAttention_52759378264454)
constexpr int T_SEQ = 1024;
constexpr int BATCH = 8;
constexpr int DIN   = 256;
constexpr int NH    = 8;
constexpr int EH    = 512;
constexpr int HE    = NH * EH;   // 4096
constexpr float SCALE = 0.044194173824159216f; // 1/sqrt(512)

typedef __attribute__((ext_vector_type(8)))  short s16x8;
typedef __attribute__((ext_vector_type(4)))  short s16x4;
typedef __attribute__((ext_vector_type(16))) float f32x16;

__device__ __forceinline__ short f2bf(float f) {
  union { float f; uint32_t u; } c; c.f = f;
  uint32_t u = c.u;
  u += 0x7fffu + ((u >> 16) & 1u);   // RNE
  return (short)(u >> 16);
}
__device__ __forceinline__ float bf2f(short s) {
  union { uint32_t u; float f; } c; c.u = ((uint32_t)(uint16_t)s) << 16;
  return c.f;
}

// async global->LDS, 16B/lane. LDS dest = wave-uniform base + lane*16 (HW).
__device__ __forceinline__ void gload16(const short* g, short* l) {
  __builtin_amdgcn_global_load_lds(
      (__attribute__((address_space(1))) void*)(void*)const_cast<short*>(g),
      (__attribute__((address_space(3))) void*)(void*)l, 16, 0, 0);
}

#define WAITVM(N) asm volatile("s_waitcnt vmcnt(" #N ")" ::: "memory")
#define BARF do { asm volatile("" ::: "memory"); __builtin_amdgcn_s_barrier(); \
                  asm volatile("" ::: "memory"); } while (0)
#define MF(A, B, C) __builtin_amdgcn_mfma_f32_32x32x16_bf16(A, B, C, 0, 0, 0)
#define LD8(p) (*(const s16x8*)(p))

// ---------------------------------------------------------------------------
// m201-style 8-wave 256x256 GEMM, BK=64, mfma_f32_32x32x16_bf16.
// 4 phases per K-tile, 8-MFMA clusters, counted vmcnt(2) once per K-tile.
// Waves: wm = wv>>2 (2), wn = wv&3 (4); per-wave C = 128x64 = 4mi x 2ni.
// LDS (128 KB): 2 bufs x {Ah0,Ah1,Bh0,Bh1}, half = [128 rows][64 cols] bf16
// = 16 KB, M-split (Ah0 = A rows 0-127 etc).
// Swizzle: row of 8 x 16B chunks; chunk cp holds source col16 cp ^ (row&7)
// (involution; applied on pre-swizzled global source AND on the read).
// Phase layout per K-tile t (buf p = t&1), ks = 16-wide k-slices 0..3:
//  P1: rd B(ni01,ks01)+A(mi01,ks01); stage Bh1(t+1)->q; bar; 8 MFMA acc[0..1]; bar
//  P2: rd A(mi23,ks01);              stage Ah0(t+1)->q; bar; 8 MFMA acc[2..3]; bar
//  P3: rd B(ni01,ks23)+A(mi01,ks23); stage Ah1(t+1)->q; bar; 8 MFMA acc[0..1]; bar
//  P4: rd A(mi23,ks23); stage Bh0(t+2)->p (B region of p dead after P3,
//      issued after P3 trailing barrier); WAITVM(2); bar; 8 MFMA; bar
// Ledger: tile t+1 halves staged at [t-1P4, tP1, tP2, tP3]; at tP4's wait the
// only newer issue is Bh0(t+2) (2 loads) -> vmcnt(2) proves t+1 landed.
// ---------------------------------------------------------------------------
template<int NT>   // K = NT*64, NT >= 2
__device__ __forceinline__ void gemm8ph(const short* __restrict__ Ag, int lda,
                                        const short* __restrict__ Bg, int ldb,
                                        short* lds, f32x16 (&acc)[4][2])
{
  const int tid = threadIdx.x;           // 512
  const int l = tid & 63, wv = tid >> 6;
  const int g = l >> 5;                  // k-subgroup (A/B frag hi half)
  const int wm = wv >> 2, wn = wv & 3;

  // read-side bases (shorts, relative to buf base) and swizzled k-offsets
  const short* Ab0 = lds + wm * 8192 + (l & 31) * 64;
  const short* Bb0 = lds + 16384 + (wn >> 1) * 8192 + ((wn & 1) * 64 + (l & 31)) * 64;
  int x[4];
#pragma unroll
  for (int ks = 0; ks < 4; ++ks) x[ks] = ((ks * 2 + g) ^ (l & 7)) * 8;

  // stage-side: thread covers chunks tid and tid+512 of a [128][8chunk] half
  const int rw = tid >> 3;
  const int sc = ((tid & 7) ^ (rw & 7)) * 8;
  auto stg = [&](int t, int h, const short* G, int ld, int R0) {
    short* dst = lds + (t & 1) * 32768 + h * 8192 + wv * 512;
    const short* src = G + (size_t)(R0 + rw) * ld + t * 64 + sc;
    gload16(src, dst);
    gload16(src + (size_t)64 * ld, dst + 4096);
  };

  // prologue: tile0 all halves + Bh0(1); then the steady pattern continues
  stg(0, 0, Ag, lda, 0);
  stg(0, 1, Ag, lda, 128);
  stg(0, 2, Bg, ldb, 0);
  stg(0, 3, Bg, ldb, 128);
  stg(1, 2, Bg, ldb, 0);
  WAITVM(2);
  BARF;

  s16x8 a[4], b[4];
#pragma unroll 1
  for (int t = 0; t < NT; ++t) {
    const short* Ab = Ab0 + (t & 1) * 32768;
    const short* Bb = Bb0 + (t & 1) * 32768;
    // ---------------- P1 ----------------
    b[0] = LD8(Bb + x[0]); b[1] = LD8(Bb + 2048 + x[0]);
    b[2] = LD8(Bb + x[1]); b[3] = LD8(Bb + 2048 + x[1]);
    a[0] = LD8(Ab + x[0]); a[1] = LD8(Ab + 2048 + x[0]);
    a[2] = LD8(Ab + x[1]); a[3] = LD8(Ab + 2048 + x[1]);
    if (t + 1 < NT) stg(t + 1, 3, Bg, ldb, 128);
    BARF;
    __builtin_amdgcn_s_setprio(1);
    acc[0][0] = MF(a[0], b[0], acc[0][0]);
    acc[0][1] = MF(a[0], b[1], acc[0][1]);
    acc[1][0] = MF(a[1], b[0], acc[1][0]);
    acc[1][1] = MF(a[1], b[1], acc[1][1]);
    acc[0][0] = MF(a[2], b[2], acc[0][0]);
    acc[0][1] = MF(a[2], b[3], acc[0][1]);
    acc[1][0] = MF(a[3], b[2], acc[1][0]);
    acc[1][1] = MF(a[3], b[3], acc[1][1]);
    __builtin_amdgcn_s_setprio(0);
    BARF;
    // ---------------- P2 ----------------
    a[0] = LD8(Ab + 2 * 2048 + x[0]); a[1] = LD8(Ab + 3 * 2048 + x[0]);
    a[2] = LD8(Ab + 2 * 2048 + x[1]); a[3] = LD8(Ab + 3 * 2048 + x[1]);
    if (t + 1 < NT) stg(t + 1, 0, Ag, lda, 0);
    BARF;
    __builtin_amdgcn_s_setprio(1);
    acc[2][0] = MF(a[0], b[0], acc[2][0]);
    acc[2][1] = MF(a[0], b[1], acc[2][1]);
    acc[3][0] = MF(a[1], b[0], acc[3][0]);
    acc[3][1] = MF(a[1], b[1], acc[3][1]);
    acc[2][0] = MF(a[2], b[2], acc[2][0]);
    acc[2][1] = MF(a[2], b[3], acc[2][1]);
    acc[3][0] = MF(a[3], b[2], acc[3][0]);
    acc[3][1] = MF(a[3], b[3], acc[3][1]);
    __builtin_amdgcn_s_setprio(0);
    BARF;
    // ---------------- P3 ----------------
    b[0] = LD8(Bb + x[2]); b[1] = LD8(Bb + 2048 + x[2]);
    b[2] = LD8(Bb + x[3]); b[3] = LD8(Bb + 2048 + x[3]);
    a[0] = LD8(Ab + x[2]); a[1] = LD8(Ab + 2048 + x[2]);
    a[2] = LD8(Ab + x[3]); a[3] = LD8(Ab + 2048 + x[3]);
    if (t + 1 < NT) stg(t + 1, 1, Ag, lda, 128);
    BARF;
    __builtin_amdgcn_s_setprio(1);
    acc[0][0] = MF(a[0], b[0], acc[0][0]);
    acc[0][1] = MF(a[0], b[1], acc[0][1]);
    acc[1][0] = MF(a[1], b[0], acc[1][0]);
    acc[1][1] = MF(a[1], b[1], acc[1][1]);
    acc[0][0] = MF(a[2], b[2], acc[0][0]);
    acc[0][1] = MF(a[2], b[3], acc[0][1]);
    acc[1][0] = MF(a[3], b[2], acc[1][0]);
    acc[1][1] = MF(a[3], b[3], acc[1][1]);
    __builtin_amdgcn_s_setprio(0);
    BARF;
    // ---------------- P4 ----------------
    a[0] = LD8(Ab + 2 * 2048 + x[2]); a[1] = LD8(Ab + 3 * 2048 + x[2]);
    a[2] = LD8(Ab + 2 * 2048 + x[3]); a[3] = LD8(Ab + 3 * 2048 + x[3]);
    if (t + 2 < NT) {
      stg(t + 2, 2, Bg, ldb, 0);
      WAITVM(2);
    } else {
      WAITVM(0);
    }
    BARF;
    __builtin_amdgcn_s_setprio(1);
    acc[2][0] = MF(a[0], b[0], acc[2][0]);
    acc[2][1] = MF(a[0], b[1], acc[2][1]);
    acc[3][0] = MF(a[1], b[0], acc[3][0]);
    acc[3][1] = MF(a[1], b[1], acc[3][1]);
    acc[2][0] = MF(a[2], b[2], acc[2][0]);
    acc[2][1] = MF(a[2], b[3], acc[2][1]);
    acc[3][0] = MF(a[3], b[2], acc[3][0]);
    acc[3][1] = MF(a[3], b[3], acc[3][1]);
    __builtin_amdgcn_s_setprio(0);
    BARF;
  }
}

// C coordinates (32x32 frag, 2wm x 4wn wave map)
#define CROW(mi, reg) ((wv >> 2) * 128 + (mi) * 32 + ((reg) & 3) + 8 * ((reg) >> 2) + 4 * hi)
#define CCOL(ni)      ((wv & 3) * 64 + (ni) * 32 + (l & 31))

// ---------------------------------------------------------------------------
// K0: fused fp32->bf16 cast; Qb transposed to [b][t][d]; weights copied.
// ---------------------------------------------------------------------------
__global__ __launch_bounds__(256) void k_cvt_all(
    const float* __restrict__ Q,  const float* __restrict__ Wq,
    const float* __restrict__ Wk, const float* __restrict__ Wv,
    const float* __restrict__ Wo, short* __restrict__ dst)
{
  constexpr int N_Q = 524288;              // 1024*8*256/4
  constexpr int N_W = 262144;              // 8*512*256/4
  constexpr int TOT = N_Q + 4 * N_W;
  int i  = blockIdx.x * 256 + threadIdx.x;
  int st = gridDim.x * 256;
  for (; i < TOT; i += st) {
    const float* s; int off;
    if (i < N_Q) {
      int b = i >> 16, t = (i >> 6) & 1023, d4 = i & 63;
      s = Q; off = (t * 8 + b) * 64 + d4;
    }
    else if (i < N_Q + N_W)     { s = Wq; off = i - N_Q; }
    else if (i < N_Q + 2 * N_W) { s = Wk; off = i - N_Q - N_W; }
    else if (i < N_Q + 3 * N_W) { s = Wv; off = i - N_Q - 2 * N_W; }
    else                        { s = Wo; off = i - N_Q - 3 * N_W; }
    float4 v = ((const float4*)s)[off];
    s16x4 o = { f2bf(v.x), f2bf(v.y), f2bf(v.z), f2bf(v.w) };
    ((s16x4*)dst)[i] = o;
  }
}

// ---------------------------------------------------------------------------
// K1a: Q/K projection. C[m,e] = sum_d Qb[m,d]*W[h,e,d] + bias.
// 1-D grid 128*HG: bx&7 -> XCD (A-tile L2 reuse). NT = 4.
// ---------------------------------------------------------------------------
__global__ __launch_bounds__(512, 2) void k_projqk(
    const short* __restrict__ Qb,
    const short* __restrict__ Wqb, const short* __restrict__ Wkb,
    const float* __restrict__ bq, const float* __restrict__ bk,
    short* __restrict__ qb, short* __restrict__ kb, int h0, int HG)
{
  __shared__ short lds[65536];
  int f = blockIdx.x;
  int bx = (f & 7) + 8 * ((f >> 3) & 3);
  int rest = f >> 5;
  int by = rest & 1, z = rest >> 1;           // z in [0, 2HG)
  int p = z / HG, hh = z % HG, h = h0 + hh;

  const short* W    = (p == 0 ? Wqb : Wkb) + ((size_t)h * EH + (size_t)by * 256) * DIN;
  const float* bias = (p == 0 ? bq  : bk ) + h * EH + by * 256;
  short* outp       = (p == 0 ? qb  : kb ) + (size_t)hh * BATCH * T_SEQ * EH;
  const short* Ag   = Qb + (size_t)bx * 256 * DIN;

  f32x16 acc[4][2] = {};
  gemm8ph<DIN / 64>(Ag, DIN, W, DIN, lds, acc);

  const int l = threadIdx.x & 63, wv = threadIdx.x >> 6, hi = l >> 5;
#pragma unroll
  for (int ni = 0; ni < 2; ++ni) {
    int coll = CCOL(ni);
    float bia = bias[coll];
    int e = by * 256 + coll;
#pragma unroll
    for (int mi = 0; mi < 4; ++mi)
#pragma unroll
      for (int reg = 0; reg < 16; ++reg) {
        int m = bx * 256 + CROW(mi, reg);
        outp[(size_t)m * EH + e] = f2bf(acc[mi][ni][reg] + bia);
      }
  }
}

// ---------------------------------------------------------------------------
// K1b: V projection TRANSPOSED: C[e, m] = sum_d Wv[h,e,d]*Qb[m,d] + bv[h,e]
// -> vT[hh][e][m], m = b*1024 + t.  1-D grid 64*HG. NT = 4.
// ---------------------------------------------------------------------------
__global__ __launch_bounds__(512, 2) void k_projv(
    const short* __restrict__ Qb, const short* __restrict__ Wvb,
    const float* __restrict__ bv, short* __restrict__ vT, int h0, int HG)
{
  __shared__ short lds[65536];
  int f = blockIdx.x;
  int bn = (f & 7) + 8 * ((f >> 3) & 3);      // [0,32) m-tile
  int rest = f >> 5;
  int bm = rest & 1, hh = rest >> 1, h = h0 + hh;

  const short* Ag = Wvb + ((size_t)h * EH + (size_t)bm * 256) * DIN;
  const short* Bg = Qb + (size_t)bn * 256 * DIN;

  f32x16 acc[4][2] = {};
  gemm8ph<DIN / 64>(Ag, DIN, Bg, DIN, lds, acc);

  short* outp = vT + (size_t)hh * EH * (BATCH * T_SEQ);
  const int l = threadIdx.x & 63, wv = threadIdx.x >> 6, hi = l >> 5;
#pragma unroll
  for (int ni = 0; ni < 2; ++ni) {
    int m = bn * 256 + CCOL(ni);
#pragma unroll
    for (int mi = 0; mi < 4; ++mi)
#pragma unroll
      for (int reg = 0; reg < 16; ++reg) {
        int e = bm * 256 + CROW(mi, reg);
        float bia = bv[h * EH + e];
        outp[(size_t)e * (BATCH * T_SEQ) + m] = f2bf(acc[mi][ni][reg] + bia);
      }
  }
}

// ---------------------------------------------------------------------------
// K3a: P[t,s] = exp(SCALE*q.k) bf16 (unnormalized) + per-block column sums.
// 1-D grid 128*HG; same-z blocks grouped per XCD. NT = 8.
// ---------------------------------------------------------------------------
__global__ __launch_bounds__(512, 2) void k_pgen(
    const short* __restrict__ qb, const short* __restrict__ kb,
    short* __restrict__ Pbuf, float* __restrict__ colpart, int HG)
{
  __shared__ short lds[65536];
  int f = blockIdx.x;
  int xcd = f & 7, gidx = f >> 3;
  int z = xcd * HG + gidx % HG;
  int tile = gidx / HG;                       // [0,16)
  int bx = tile & 3, by = tile >> 2;

  const short* Ag = qb + (size_t)z * T_SEQ * EH + (size_t)bx * 256 * EH;
  const short* Bg = kb + (size_t)z * T_SEQ * EH + (size_t)by * 256 * EH;

  f32x16 acc[4][2] = {};
  gemm8ph<EH / 64>(Ag, EH, Bg, EH, lds, acc);

  short* Pb = Pbuf + (size_t)z * T_SEQ * T_SEQ;
  const int l = threadIdx.x & 63, wv = threadIdx.x >> 6, hi = l >> 5;

  float cs[2] = {0.f, 0.f};
#pragma unroll
  for (int ni = 0; ni < 2; ++ni) {
    int s = by * 256 + CCOL(ni);
#pragma unroll
    for (int mi = 0; mi < 4; ++mi)
#pragma unroll
      for (int reg = 0; reg < 16; ++reg) {
        int tq = bx * 256 + CROW(mi, reg);
        float ev = __expf(acc[mi][ni][reg] * SCALE);
        cs[ni] += ev;
        Pb[(size_t)tq * T_SEQ + s] = f2bf(ev);
      }
  }
  cs[0] += __shfl_xor(cs[0], 32);
  cs[1] += __shfl_xor(cs[1], 32);
  __syncthreads();
  float* csL = (float*)lds;                   // [2 wm][256 cols]
  if (l < 32) {
#pragma unroll
    for (int ni = 0; ni < 2; ++ni)
      csL[(wv >> 2) * 256 + (wv & 3) * 64 + ni * 32 + l] = cs[ni];
  }
  __syncthreads();
  if (threadIdx.x < 256) {
    float tot = csL[threadIdx.x] + csL[256 + threadIdx.x];
    colpart[((size_t)z * 4 + bx) * T_SEQ + by * 256 + threadIdx.x] = tot;
  }
}

// ---------------------------------------------------------------------------
// K2: scale V in place by the softmax normalizer (fused invsum):
// vT[hh][e][m] *= 1 / sum_p colpart[(z*4+p)][t],  z = hh*8+b, m = b*1024+t
// ---------------------------------------------------------------------------
__global__ __launch_bounds__(256) void k_scalev(
    short* __restrict__ vT, const float* __restrict__ colpart, int HG)
{
  __shared__ float invL[1024];
  const int et = blockIdx.x, z = blockIdx.y;
  const int hh = z >> 3, b = z & 7;
  const int tid = threadIdx.x;

#pragma unroll
  for (int it = 0; it < 4; ++it) {
    int t = it * 256 + tid;
    float s = 0.f;
#pragma unroll
    for (int p = 0; p < 4; ++p) s += colpart[((size_t)z * 4 + p) * T_SEQ + t];
    invL[t] = 1.0f / s;
  }
  __syncthreads();

  short* base = vT + (size_t)hh * EH * (BATCH * T_SEQ)
                   + (size_t)et * 64 * (BATCH * T_SEQ) + (size_t)b * T_SEQ;
  for (int c = tid; c < 64 * 128; c += 256) {
    int row = c >> 7, col = (c & 127) * 8;
    short* p = &base[(size_t)row * (BATCH * T_SEQ) + col];
    s16x8 v = *(s16x8*)p;
#pragma unroll
    for (int j = 0; j < 8; ++j) v[j] = f2bf(bf2f(v[j]) * invL[col + j]);
    *(s16x8*)p = v;
  }
}

// ---------------------------------------------------------------------------
// K3b: O[t,e] = sum_s P[t,s]*vT[e,s] -> Hmat[(b*T+t), h*EH+e]
// 1-D grid 64*HG; same-z grouped per XCD. NT = 16.
// ---------------------------------------------------------------------------
__global__ __launch_bounds__(512, 2) void k_ogemm(
    const short* __restrict__ Pbuf, const short* __restrict__ vT,
    short* __restrict__ Hmat, int h0, int HG)
{
  __shared__ short lds[65536];
  int f = blockIdx.x;
  int xcd = f & 7, gidx = f >> 3;
  int z = xcd * HG + gidx % HG;
  int rb = gidx / HG;                         // [0,8)
  int bx = rb & 3, by = rb >> 2;
  const int hh = z >> 3, b = z & 7, h = h0 + hh;

  const short* Ag = Pbuf + (size_t)z * T_SEQ * T_SEQ + (size_t)bx * 256 * T_SEQ;
  const short* Bg = vT + ((size_t)hh * EH + (size_t)by * 256) * (BATCH * T_SEQ)
                       + (size_t)b * T_SEQ;

  f32x16 acc[4][2] = {};
  gemm8ph<T_SEQ / 64>(Ag, T_SEQ, Bg, BATCH * T_SEQ, lds, acc);

  const int l = threadIdx.x & 63, wv = threadIdx.x >> 6, hi = l >> 5;
#pragma unroll
  for (int ni = 0; ni < 2; ++ni) {
    int e = by * 256 + CCOL(ni);
#pragma unroll
    for (int mi = 0; mi < 4; ++mi)
#pragma unroll
      for (int reg = 0; reg < 16; ++reg) {
        int tq = bx * 256 + CROW(mi, reg);
        Hmat[((size_t)b * T_SEQ + tq) * HE + (size_t)h * EH + e] = f2bf(acc[mi][ni][reg]);
      }
  }
}

// ---------------------------------------------------------------------------
// K4a: split-K(8) output GEMM. part[ks][m][d], K-slice 512, NT = 8.
// 1-D grid 256.
// ---------------------------------------------------------------------------
__global__ __launch_bounds__(512, 2) void k_final(
    const short* __restrict__ Hmat, const short* __restrict__ Wob,
    float* __restrict__ part)
{
  __shared__ short lds[65536];
  int f = blockIdx.x;
  int swz = (f & 7) * 32 + (f >> 3);          // nwg = 256
  const int bx = swz & 31, ks = swz >> 5;

  const short* Ag = Hmat + (size_t)bx * 256 * HE + (size_t)ks * 512;
  const short* Bg = Wob  + (size_t)ks * 512;

  f32x16 acc[4][2] = {};
  gemm8ph<512 / 64>(Ag, HE, Bg, HE, lds, acc);

  float* pp = part + (size_t)ks * (T_SEQ * BATCH) * DIN;
  const int l = threadIdx.x & 63, wv = threadIdx.x >> 6, hi = l >> 5;
#pragma unroll
  for (int ni = 0; ni < 2; ++ni) {
    int d = CCOL(ni);
#pragma unroll
    for (int mi = 0; mi < 4; ++mi)
#pragma unroll
      for (int reg = 0; reg < 16; ++reg) {
        int m = bx * 256 + CROW(mi, reg);
        pp[(size_t)m * DIN + d] = acc[mi][ni][reg];
      }
  }
}

// K4b: out[(t*B+b), d] = sum_ks part[ks][(b*T+t)][d] + bo[d]
__global__ __launch_bounds__(256) void k_red(const float* __restrict__ part,
                                             const float* __restrict__ bo,
                                             float* __restrict__ out)
{
  int i = blockIdx.x * 256 + threadIdx.x;   // over 8192*64 float4s
  int m = i >> 6, d4 = i & 63;
  float4 s = ((const float4*)part)[i];
#pragma unroll
  for (int ks = 1; ks < 8; ++ks) {
    float4 p = ((const float4*)(part + (size_t)ks * T_SEQ * BATCH * DIN))[i];
    s.x += p.x; s.y += p.y; s.z += p.z; s.w += p.w;
  }
  float4 b4 = ((const float4*)bo)[d4];
  s.x += b4.x; s.y += b4.y; s.z += b4.z; s.w += b4.w;
  int t = m & 1023, b = m >> 10;
  ((float4*)out)[(t * 8 + b) * 64 + d4] = s;
}

// ---------------------------------------------------------------------------
extern "C" void kernel_launch(void* const* d_in, const int* in_sizes, int n_in,
                              void* d_out, int out_size, void* d_ws, size_t ws_size,
                              hipStream_t stream)
{
  const float* Q  = (const float*)d_in[0];
  const float* Wq = (const float*)d_in[1];
  const float* bq = (const float*)d_in[2];
  const float* Wk = (const float*)d_in[3];
  const float* bk = (const float*)d_in[4];
  const float* Wv = (const float*)d_in[5];
  const float* bv = (const float*)d_in[6];
  const float* Wo = (const float*)d_in[7];
  const float* bo = (const float*)d_in[8];
  float* out = (float*)d_out;

  // ---- sizes ----
  const size_t QB_B   = (size_t)T_SEQ * BATCH * DIN * 2;       //  4 MiB
  const size_t W_B    = (size_t)NH * EH * DIN * 2;             //  2 MiB each
  const size_t WO_B   = (size_t)DIN * HE * 2;                  //  2 MiB
  const size_t HMAT_B = (size_t)T_SEQ * BATCH * HE * 2;        // 64 MiB
  const size_t PART_B = (size_t)8 * T_SEQ * BATCH * DIN * 4;   // 64 MiB
  const size_t QKV1   = (size_t)BATCH * T_SEQ * EH * 2;        //  8 MiB / head
  const size_t P1     = (size_t)BATCH * T_SEQ * T_SEQ * 2;     // 16 MiB / head
  const size_t CP1    = (size_t)BATCH * 4 * T_SEQ * 4;         // 128 KiB / head
  const size_t inputsB = QB_B + 3 * W_B + WO_B;                // 12 MiB contiguous

  // ---- largest HG whose plan fits (alias: part <-> P) ----
  int HG = 8;
  for (; HG > 1; HG >>= 1) {
    size_t share = ((size_t)HG * P1 > PART_B) ? (size_t)HG * P1 : PART_B;
    size_t tot = inputsB + 3 * (size_t)HG * QKV1 + share + HMAT_B
               + (size_t)HG * CP1 + 8192;
    if (tot <= ws_size) break;
  }
  size_t shareB = ((size_t)HG * P1 > PART_B) ? (size_t)HG * P1 : PART_B;

  char* w = (char*)d_ws;
  auto alloc = [&](size_t bytes) {
    char* p = w;
    w += (bytes + 255) & ~(size_t)255;
    return p;
  };
  short* Qb   = (short*)alloc(QB_B);
  short* Wqb  = (short*)alloc(W_B);
  short* Wkb  = (short*)alloc(W_B);
  short* Wvb  = (short*)alloc(W_B);
  short* Wob  = (short*)alloc(WO_B);
  float* cpart= (float*)alloc((size_t)HG * CP1);
  short* qb   = (short*)alloc((size_t)HG * QKV1);
  short* kb   = (short*)alloc((size_t)HG * QKV1);
  short* vT   = (short*)alloc((size_t)HG * QKV1);
  char*  shr  = alloc(shareB);                      // P during loop; part after
  short* Hmat = (short*)alloc(HMAT_B);

  short* Pbuf = (short*)shr;
  float* part = (float*)shr;

  k_cvt_all<<<dim3(2048), 256, 0, stream>>>(Q, Wq, Wk, Wv, Wo, Qb);

  for (int h0 = 0; h0 < NH; h0 += HG) {
    k_projqk<<<dim3(128 * HG), 512, 0, stream>>>(Qb, Wqb, Wkb, bq, bk,
                                                 qb, kb, h0, HG);
    k_projv <<<dim3(64 * HG), 512, 0, stream>>>(Qb, Wvb, bv, vT, h0, HG);
    k_pgen  <<<dim3(128 * HG), 512, 0, stream>>>(qb, kb, Pbuf, cpart, HG);
    k_scalev<<<dim3(8, HG * 8), 256, 0, stream>>>(vT, cpart, HG);
    k_ogemm <<<dim3(64 * HG), 512, 0, stream>>>(Pbuf, vT, Hmat, h0, HG);
  }
  k_final<<<dim3(256), 512, 0, stream>>>(Hmat, Wob, part);
  k_red  <<<dim3(T_SEQ * BATCH * DIN / 4 / 256), 256, 0, stream>>>(part, bo, out);
}